// Round 5
// baseline (17764.218 us; speedup 1.0000x reference)
//
#include <hip/hip_runtime.h>
#include <math.h>

// ---- problem constants ----
constexpr int B    = 128;
constexpr int PAST = 256;
constexpr int FUT  = 128;
constexpr int D    = 128;
constexpr int RU   = 512;
constexpr int LD   = 128;
constexpr int TL   = 128;
constexpr int HDEC = 640;

typedef __bf16 bf16x8 __attribute__((ext_vector_type(8)));
typedef float  f32x4  __attribute__((ext_vector_type(4)));
typedef unsigned short u16x8 __attribute__((ext_vector_type(8)));

__device__ __forceinline__ unsigned short f2bf(float f) {
    unsigned int x = __float_as_uint(f);
    x = (x + 0x7fffu + ((x >> 16) & 1u)) >> 16;
    return (unsigned short)x;
}
__device__ __forceinline__ float bf2f(unsigned short u) {
    return __uint_as_float(((unsigned int)u) << 16);
}
__device__ __forceinline__ float sigm_(float x) { return 1.f / (1.f + __expf(-x)); }
__device__ __forceinline__ float tanh_(float x) {
    float e = __expf(2.f * x);
    return 1.f - 2.f / (e + 1.f);
}
__device__ __forceinline__ bf16x8 ldsfrag(const unsigned short* p) {
    return *reinterpret_cast<const bf16x8*>(p);
}
__device__ __forceinline__ f32x4 mfma16(bf16x8 a, bf16x8 b, f32x4 c) {
    return __builtin_amdgcn_mfma_f32_16x16x32_bf16(a, b, c, 0, 0, 0);
}
__device__ __forceinline__ void cvt4(const float4& v, uint2& hp, uint2& lp) {
    float a[4] = {v.x, v.y, v.z, v.w};
    unsigned short hs[4], ls[4];
    #pragma unroll
    for (int q = 0; q < 4; ++q) { hs[q] = f2bf(a[q]); ls[q] = f2bf(a[q] - bf2f(hs[q])); }
    hp.x = (unsigned)hs[0] | ((unsigned)hs[1] << 16);
    hp.y = (unsigned)hs[2] | ((unsigned)hs[3] << 16);
    lp.x = (unsigned)ls[0] | ((unsigned)ls[1] << 16);
    lp.y = (unsigned)ls[2] | ((unsigned)ls[3] << 16);
}

// monotonic-counter subset barrier (device scope; cross-XCD safe).
// All participating WGs are co-resident by construction: 1 block/CU (LDS-bound),
// grid <= 256, nothing else on the device.
__device__ __forceinline__ void coop_barrier(unsigned* cnt, unsigned nwg, unsigned rnd) {
    __syncthreads();
    __threadfence();
    if (threadIdx.x == 0) {
        __hip_atomic_fetch_add(cnt, 1u, __ATOMIC_RELEASE, __HIP_MEMORY_SCOPE_AGENT);
        unsigned tgt = (rnd + 1u) * nwg;
        while (__hip_atomic_load(cnt, __ATOMIC_ACQUIRE, __HIP_MEMORY_SCOPE_AGENT) < tgt)
            __builtin_amdgcn_s_sleep(2);
    }
    __syncthreads();
}

// ======================= weight conversion =======================
__global__ __launch_bounds__(256) void split_plain(
    const float* __restrict__ W, unsigned short* __restrict__ hi,
    unsigned short* __restrict__ lo, int n)
{
    for (int i = blockIdx.x * 256 + threadIdx.x; i < n; i += gridDim.x * 256) {
        float v = W[i];
        unsigned short h = f2bf(v);
        hi[i] = h;
        lo[i] = f2bf(v - bf2f(h));
    }
}

__global__ __launch_bounds__(256) void split_pack(
    const float* __restrict__ Wih, const float* __restrict__ Whh,
    int DXc, int Hc, int N3,
    unsigned short* __restrict__ hi, unsigned short* __restrict__ lo)
{
    int K = DXc + Hc;
    int total = N3 * K;
    for (int i = blockIdx.x * 256 + threadIdx.x; i < total; i += gridDim.x * 256) {
        int n = i / K, k = i - n * K;
        float v = (k < DXc) ? Wih[(size_t)n * DXc + k]
                            : Whh[(size_t)n * Hc + (k - DXc)];
        unsigned short h = f2bf(v);
        hi[i] = h;
        lo[i] = f2bf(v - bf2f(h));
    }
}

// ======================= persistent encoder (phi + xr) =======================
struct EncArgs {
    const float* x; int xstride; int T;
    const unsigned short* Whi; const unsigned short* Wlo;  // packed (3*512, 640)
    const float* bih; const float* bhh;
    float* h0; float* h1;     // ping-pong (B, 512)
    unsigned* bar;
};

// 128 WGs x 256 thr. WGs 0..63: P, 64..127: X.
// per WG: 64 rows (m0) x 16 h-cols (c0). wave w -> rows m0+w*16..+15, all 3 gates.
__global__ __launch_bounds__(256, 1) void enc_kernel(EncArgs P, EncArgs X)
{
    constexpr int H = 512, DX = 128, K = 640, NCH = 20, XC = 4, LDK = 648, SR = 40;
    __shared__ unsigned short sWhi[48 * LDK];
    __shared__ unsigned short sAh[2][64 * SR];
    __shared__ unsigned short sAl[2][64 * SR];
    __shared__ unsigned short sWl[2][48 * SR];

    const int wg = blockIdx.x;
    const EncArgs A = (wg < 64) ? P : X;
    const int lwg = wg & 63;
    const int m0  = (lwg & 1) * 64;
    const int c0  = (lwg >> 1) * 16;
    const int tid = threadIdx.x;
    const int lane = tid & 63;
    const int w = tid >> 6;
    const int arow = lane & 15;
    const int koff = (lane >> 4) * 8;

    // one-time W-hi resident fill: 48 rows x 640
    for (int i = tid; i < 48 * 80; i += 256) {
        int rr = i / 80, c8 = i % 80;
        int g = rr >> 4, j = rr & 15;
        *reinterpret_cast<u16x8*>(&sWhi[rr * LDK + c8 * 8]) =
            *reinterpret_cast<const u16x8*>(A.Whi + (size_t)(g * H + c0 + j) * K + c8 * 8);
    }
    const unsigned short* wloB = nullptr;
    if (tid < 192) {
        int rr = tid >> 2, c8 = tid & 3;
        int g = rr >> 4, j = rr & 15;
        wloB = A.Wlo + (size_t)(g * H + c0 + j) * K + c8 * 8;
    }
    const int hc = c0 + arow;
    const float brz0 = A.bih[hc] + A.bhh[hc];
    const float brz1 = A.bih[H + hc] + A.bhh[H + hc];
    const float bn_i = A.bih[2 * H + hc];
    const float bn_h = A.bhh[2 * H + hc];
    __syncthreads();

    float4 ar[2]; u16x8 wl;

    for (int t = 0; t < A.T; ++t) {
        const float* hin  = (t & 1) ? A.h1 : A.h0;
        float*       hout = (t & 1) ? A.h0 : A.h1;
        const float* xp = A.x + (size_t)t * D;

        f32x4 accR = {0,0,0,0}, accZ = {0,0,0,0}, accNx = {0,0,0,0}, accNh = {0,0,0,0};

        auto ldc = [&](int c) {
            int k0 = c * 32;
            #pragma unroll
            for (int j = 0; j < 2; ++j) {
                int id = tid + j * 256;
                int row = id >> 3, c4 = id & 7;
                const float* src = (k0 < DX)
                    ? (xp + (size_t)(m0 + row) * A.xstride + k0 + c4 * 4)
                    : (hin + (size_t)(m0 + row) * H + (k0 - DX) + c4 * 4);
                ar[j] = *reinterpret_cast<const float4*>(src);
            }
            if (wloB) wl = *reinterpret_cast<const u16x8*>(wloB + k0);
        };
        auto wrc = [&](int b) {
            #pragma unroll
            for (int j = 0; j < 2; ++j) {
                int id = tid + j * 256;
                int row = id >> 3, c4 = id & 7;
                uint2 hp, lp; cvt4(ar[j], hp, lp);
                *reinterpret_cast<uint2*>(&sAh[b][row * SR + c4 * 4]) = hp;
                *reinterpret_cast<uint2*>(&sAl[b][row * SR + c4 * 4]) = lp;
            }
            if (wloB) {
                int rr = tid >> 2, c8 = tid & 3;
                *reinterpret_cast<u16x8*>(&sWl[b][rr * SR + c8 * 8]) = wl;
            }
        };

        ldc(0); wrc(0); __syncthreads();
        for (int c = 0; c < NCH; ++c) {
            const int b = c & 1;
            if (c + 1 < NCH) ldc(c + 1);
            const int aoff = (w * 16 + arow) * SR + koff;
            bf16x8 ah = ldsfrag(&sAh[b][aoff]);
            bf16x8 al = ldsfrag(&sAl[b][aoff]);
            bf16x8 whR = ldsfrag(&sWhi[(arow) * LDK + c * 32 + koff]);
            bf16x8 whZ = ldsfrag(&sWhi[(16 + arow) * LDK + c * 32 + koff]);
            bf16x8 whN = ldsfrag(&sWhi[(32 + arow) * LDK + c * 32 + koff]);
            bf16x8 wlR = ldsfrag(&sWl[b][(arow) * SR + koff]);
            bf16x8 wlZ = ldsfrag(&sWl[b][(16 + arow) * SR + koff]);
            bf16x8 wlN = ldsfrag(&sWl[b][(32 + arow) * SR + koff]);
            accR = mfma16(ah, whR, accR); accR = mfma16(ah, wlR, accR); accR = mfma16(al, whR, accR);
            accZ = mfma16(ah, whZ, accZ); accZ = mfma16(ah, wlZ, accZ); accZ = mfma16(al, whZ, accZ);
            if (c < XC) {
                accNx = mfma16(ah, whN, accNx); accNx = mfma16(ah, wlN, accNx); accNx = mfma16(al, whN, accNx);
            } else {
                accNh = mfma16(ah, whN, accNh); accNh = mfma16(ah, wlN, accNh); accNh = mfma16(al, whN, accNh);
            }
            if (c + 1 < NCH) wrc(b ^ 1);
            __syncthreads();
        }

        #pragma unroll
        for (int r = 0; r < 4; ++r) {
            int m = m0 + w * 16 + (lane >> 4) * 4 + r;
            float rg = sigm_(accR[r] + brz0);
            float zg = sigm_(accZ[r] + brz1);
            float ng = tanh_((accNx[r] + bn_i) + rg * (accNh[r] + bn_h));
            float ho = hin[(size_t)m * H + hc];
            hout[(size_t)m * H + hc] = (1.f - zg) * ng + zg * ho;
        }
        coop_barrier(A.bar, 64, (unsigned)t);
    }
}

// ======================= persistent decoder =======================
struct DecArgs {
    const float* past_last;    // past + 255*D, row stride PAST*D
    float* xmu;                // d_out, (B, TL, D)
    const unsigned short* Whi; const unsigned short* Wlo;   // dec packed (1920, 768)
    const float* bih; const float* bhh;
    const unsigned short* fcWhi; const unsigned short* fcWlo; // (512, 640)
    const float* fc_b;
    const unsigned short* oWhi; const unsigned short* oWlo;   // (128, 512)
    const float* out_b;
    float* dh0; float* dh1; float* fcb;
    unsigned* bar;
};

// plain streamed GEMM for one 16-col tile, M=128, per-wave 2 m-frags
__device__ __forceinline__ void plain16(
    unsigned short* smem, int whi_ush, int ldk, int nch,
    const float* src, int srcld,
    const unsigned short* wloB,
    float bias_v, int mode,
    float* dst, long dld, int dcol0,
    int tid, int w, int lane, int arow, int koff)
{
    unsigned short* AH[2] = { smem + whi_ush,          smem + whi_ush + 5120 };
    unsigned short* AL[2] = { smem + whi_ush + 10240,  smem + whi_ush + 15360 };
    unsigned short* WL[2] = { smem + whi_ush + 20480,  smem + whi_ush + 21120 };
    f32x4 acc0 = {0,0,0,0}, acc1 = {0,0,0,0};
    float4 ar[4]; u16x8 wl;
    auto ldc = [&](int c) {
        int k0 = c * 32;
        #pragma unroll
        for (int j = 0; j < 4; ++j) {
            int id = tid + j * 256, row = id >> 3, c4 = id & 7;
            ar[j] = *reinterpret_cast<const float4*>(src + (size_t)row * srcld + k0 + c4 * 4);
        }
        if (wloB) wl = *reinterpret_cast<const u16x8*>(wloB + k0);
    };
    auto wrc = [&](int b) {
        #pragma unroll
        for (int j = 0; j < 4; ++j) {
            int id = tid + j * 256, row = id >> 3, c4 = id & 7;
            uint2 hp, lp; cvt4(ar[j], hp, lp);
            *reinterpret_cast<uint2*>(&AH[b][row * 40 + c4 * 4]) = hp;
            *reinterpret_cast<uint2*>(&AL[b][row * 40 + c4 * 4]) = lp;
        }
        if (wloB) {
            int rr = tid >> 2, c8 = tid & 3;
            *reinterpret_cast<u16x8*>(&WL[b][rr * 40 + c8 * 8]) = wl;
        }
    };
    ldc(0); wrc(0); __syncthreads();
    for (int c = 0; c < nch; ++c) {
        int b = c & 1;
        if (c + 1 < nch) ldc(c + 1);
        int a0 = (w * 32 + arow) * 40 + koff;
        bf16x8 ah0 = ldsfrag(&AH[b][a0]),       al0 = ldsfrag(&AL[b][a0]);
        bf16x8 ah1 = ldsfrag(&AH[b][a0 + 640]), al1 = ldsfrag(&AL[b][a0 + 640]);
        bf16x8 wh  = ldsfrag(&smem[arow * ldk + c * 32 + koff]);
        bf16x8 wlg = ldsfrag(&WL[b][arow * 40 + koff]);
        acc0 = mfma16(ah0, wh, acc0); acc0 = mfma16(ah0, wlg, acc0); acc0 = mfma16(al0, wh, acc0);
        acc1 = mfma16(ah1, wh, acc1); acc1 = mfma16(ah1, wlg, acc1); acc1 = mfma16(al1, wh, acc1);
        if (c + 1 < nch) wrc(b ^ 1);
        __syncthreads();
    }
    #pragma unroll
    for (int mf = 0; mf < 2; ++mf) {
        f32x4 a = mf ? acc1 : acc0;
        #pragma unroll
        for (int r = 0; r < 4; ++r) {
            int m = w * 32 + mf * 16 + (lane >> 4) * 4 + r;
            float v = a[r] + bias_v;
            if (mode == 1) v = fmaxf(v, 0.f);
            dst[(size_t)m * dld + dcol0 + arow] = v;
        }
    }
}

__device__ __forceinline__ void dec_gru(
    unsigned short* smem, const DecArgs& A, int t,
    const float* hcur, float* hnext,
    int c0, const unsigned short* wloB,
    float brz0, float brz1, float bn_i, float bn_h,
    int tid, int w, int lane, int arow, int koff)
{
    unsigned short* AH[2] = { smem + 37248, smem + 42368 };
    unsigned short* AL[2] = { smem + 47488, smem + 52608 };
    unsigned short* WL[2] = { smem + 57728, smem + 59648 };
    const float* xp; long xs;
    if (t == 0) { xp = A.past_last; xs = (long)PAST * D; }
    else        { xp = A.xmu + (size_t)(t - 1) * D; xs = (long)TL * D; }

    f32x4 aR0 = {0,0,0,0}, aZ0 = aR0, aNx0 = aR0, aNh0 = aR0;
    f32x4 aR1 = aR0, aZ1 = aR0, aNx1 = aR0, aNh1 = aR0;
    float4 ar[4]; u16x8 wl;
    auto ldc = [&](int c) {
        int k0 = c * 32;
        #pragma unroll
        for (int j = 0; j < 4; ++j) {
            int id = tid + j * 256, row = id >> 3, c4 = id & 7;
            const float* s = (k0 < D)
                ? (xp + (size_t)row * xs + k0 + c4 * 4)
                : (hcur + (size_t)row * HDEC + (k0 - D) + c4 * 4);
            ar[j] = *reinterpret_cast<const float4*>(s);
        }
        if (wloB) wl = *reinterpret_cast<const u16x8*>(wloB + k0);
    };
    auto wrc = [&](int b) {
        #pragma unroll
        for (int j = 0; j < 4; ++j) {
            int id = tid + j * 256, row = id >> 3, c4 = id & 7;
            uint2 hp, lp; cvt4(ar[j], hp, lp);
            *reinterpret_cast<uint2*>(&AH[b][row * 40 + c4 * 4]) = hp;
            *reinterpret_cast<uint2*>(&AL[b][row * 40 + c4 * 4]) = lp;
        }
        if (wloB) {
            int rr = tid >> 2, c8 = tid & 3;
            *reinterpret_cast<u16x8*>(&WL[b][rr * 40 + c8 * 8]) = wl;
        }
    };
    ldc(0); wrc(0); __syncthreads();
    for (int c = 0; c < 24; ++c) {
        int b = c & 1;
        if (c + 1 < 24) ldc(c + 1);
        int a0 = (w * 32 + arow) * 40 + koff;
        bf16x8 ah0 = ldsfrag(&AH[b][a0]),       al0 = ldsfrag(&AL[b][a0]);
        bf16x8 ah1 = ldsfrag(&AH[b][a0 + 640]), al1 = ldsfrag(&AL[b][a0 + 640]);
        bf16x8 whR = ldsfrag(&smem[(arow) * 776 + c * 32 + koff]);
        bf16x8 whZ = ldsfrag(&smem[(16 + arow) * 776 + c * 32 + koff]);
        bf16x8 whN = ldsfrag(&smem[(32 + arow) * 776 + c * 32 + koff]);
        bf16x8 wlR = ldsfrag(&WL[b][(arow) * 40 + koff]);
        bf16x8 wlZ = ldsfrag(&WL[b][(16 + arow) * 40 + koff]);
        bf16x8 wlN = ldsfrag(&WL[b][(32 + arow) * 40 + koff]);
        aR0 = mfma16(ah0, whR, aR0); aR0 = mfma16(ah0, wlR, aR0); aR0 = mfma16(al0, whR, aR0);
        aR1 = mfma16(ah1, whR, aR1); aR1 = mfma16(ah1, wlR, aR1); aR1 = mfma16(al1, whR, aR1);
        aZ0 = mfma16(ah0, whZ, aZ0); aZ0 = mfma16(ah0, wlZ, aZ0); aZ0 = mfma16(al0, whZ, aZ0);
        aZ1 = mfma16(ah1, whZ, aZ1); aZ1 = mfma16(ah1, wlZ, aZ1); aZ1 = mfma16(al1, whZ, aZ1);
        if (c < 4) {
            aNx0 = mfma16(ah0, whN, aNx0); aNx0 = mfma16(ah0, wlN, aNx0); aNx0 = mfma16(al0, whN, aNx0);
            aNx1 = mfma16(ah1, whN, aNx1); aNx1 = mfma16(ah1, wlN, aNx1); aNx1 = mfma16(al1, whN, aNx1);
        } else {
            aNh0 = mfma16(ah0, whN, aNh0); aNh0 = mfma16(ah0, wlN, aNh0); aNh0 = mfma16(al0, whN, aNh0);
            aNh1 = mfma16(ah1, whN, aNh1); aNh1 = mfma16(ah1, wlN, aNh1); aNh1 = mfma16(al1, whN, aNh1);
        }
        if (c + 1 < 24) wrc(b ^ 1);
        __syncthreads();
    }
    const int hcc = c0 + arow;
    #pragma unroll
    for (int mf = 0; mf < 2; ++mf) {
        #pragma unroll
        for (int r = 0; r < 4; ++r) {
            int m = w * 32 + mf * 16 + (lane >> 4) * 4 + r;
            float vr = mf ? aR1[r] : aR0[r];
            float vz = mf ? aZ1[r] : aZ0[r];
            float vx = mf ? aNx1[r] : aNx0[r];
            float vh = mf ? aNh1[r] : aNh0[r];
            float rg = sigm_(vr + brz0);
            float zg = sigm_(vz + brz1);
            float ng = tanh_((vx + bn_i) + rg * (vh + bn_h));
            float ho = hcur[(size_t)m * HDEC + hcc];
            hnext[(size_t)m * HDEC + hcc] = (1.f - zg) * ng + zg * ho;
        }
    }
}

// 80 WGs: 0..39 GRU (16 cols each of 640), 40..71 fc (16 of 512), 72..79 out (16 of 128)
__global__ __launch_bounds__(256, 1) void dec_kernel(DecArgs A)
{
    __shared__ unsigned short smem[61568];   // 123136 B -> 1 block/CU
    const int wg = blockIdx.x;
    const int tid = threadIdx.x;
    const int lane = tid & 63;
    const int w = tid >> 6;
    const int arow = lane & 15;
    const int koff = (lane >> 4) * 8;
    const int role = (wg < 40) ? 0 : ((wg < 72) ? 1 : 2);

    const unsigned short* wloB = nullptr;
    float b0 = 0, b1 = 0, b2 = 0, b3 = 0;
    int c0 = 0;

    if (role == 0) {
        c0 = wg * 16;
        for (int i = tid; i < 4608; i += 256) {
            int rr = i / 96, c8 = i % 96;
            int g = rr >> 4, j = rr & 15;
            *reinterpret_cast<u16x8*>(&smem[rr * 776 + c8 * 8]) =
                *reinterpret_cast<const u16x8*>(A.Whi + (size_t)(g * HDEC + c0 + j) * 768 + c8 * 8);
        }
        if (tid < 192) {
            int rr = tid >> 2, c8 = tid & 3;
            int g = rr >> 4, j = rr & 15;
            wloB = A.Wlo + (size_t)(g * HDEC + c0 + j) * 768 + c8 * 8;
        }
        int hcc = c0 + arow;
        b0 = A.bih[hcc] + A.bhh[hcc];
        b1 = A.bih[HDEC + hcc] + A.bhh[HDEC + hcc];
        b2 = A.bih[2 * HDEC + hcc];
        b3 = A.bhh[2 * HDEC + hcc];
    } else if (role == 1) {
        c0 = (wg - 40) * 16;
        for (int i = tid; i < 1280; i += 256) {
            int rr = i / 80, c8 = i % 80;
            *reinterpret_cast<u16x8*>(&smem[rr * 648 + c8 * 8]) =
                *reinterpret_cast<const u16x8*>(A.fcWhi + (size_t)(c0 + rr) * 640 + c8 * 8);
        }
        if (tid < 64) {
            int rr = tid >> 2, c8 = tid & 3;
            wloB = A.fcWlo + (size_t)(c0 + rr) * 640 + c8 * 8;
        }
        b0 = A.fc_b[c0 + arow];
    } else {
        c0 = (wg - 72) * 16;
        for (int i = tid; i < 1024; i += 256) {
            int rr = i >> 6, c8 = i & 63;
            *reinterpret_cast<u16x8*>(&smem[rr * 520 + c8 * 8]) =
                *reinterpret_cast<const u16x8*>(A.oWhi + (size_t)(c0 + rr) * 512 + c8 * 8);
        }
        if (tid < 64) {
            int rr = tid >> 2, c8 = tid & 3;
            wloB = A.oWlo + (size_t)(c0 + rr) * 512 + c8 * 8;
        }
        b0 = A.out_b[c0 + arow];
    }
    __syncthreads();

    unsigned rnd = 0;
    for (int t = 0; t < TL; ++t) {
        const float* hcur = (t & 1) ? A.dh1 : A.dh0;
        float*       hnext = (t & 1) ? A.dh0 : A.dh1;
        if (role == 0)
            dec_gru(smem, A, t, hcur, hnext, c0, wloB, b0, b1, b2, b3, tid, w, lane, arow, koff);
        coop_barrier(A.bar, 80, rnd++);
        if (role == 1)
            plain16(smem, 10368, 648, 20, hnext, HDEC, wloB, b0, 1, A.fcb, 512, c0,
                    tid, w, lane, arow, koff);
        coop_barrier(A.bar, 80, rnd++);
        if (role == 2)
            plain16(smem, 8320, 520, 16, A.fcb, 512, wloB, b0, 0,
                    A.xmu + (size_t)t * D, (long)TL * D, c0, tid, w, lane, arow, koff);
        coop_barrier(A.bar, 80, rnd++);
    }
}

// ======================= MLP GEMM (r2, proven) =======================
__global__ __launch_bounds__(256, 1) void gemm_mfma(
    const float* __restrict__ A, int lda,
    const unsigned short* __restrict__ Whi, const unsigned short* __restrict__ Wlo,
    int K, const float* __restrict__ bias,
    float* __restrict__ C, int ldc, int act)
{
    constexpr int LDR = 72;
    __shared__ unsigned short sA[2][64 * LDR];
    __shared__ unsigned short sW[2][128 * LDR];

    const int m0 = blockIdx.x * 64;
    const int n0 = blockIdx.y * 128;
    const int tid = threadIdx.x;
    const int lane = tid & 63;
    const int w = tid >> 6;
    const int arow = lane & 15;
    const int koff = (lane >> 4) * 8;

    f32x4 acc[4][2];
    #pragma unroll
    for (int i = 0; i < 4; ++i) { acc[i][0] = f32x4{0,0,0,0}; acc[i][1] = f32x4{0,0,0,0}; }

    float4 ar[4];
    u16x8  wreg[8];
    const int NC = K / 64;

    auto load_chunk = [&](int c) {
        const int k0 = c * 64;
        #pragma unroll
        for (int j = 0; j < 4; ++j) {
            int id = tid + j * 256;
            int row = id >> 4, c4 = id & 15;
            ar[j] = *reinterpret_cast<const float4*>(A + (size_t)(m0 + row) * lda + k0 + c4 * 4);
        }
        #pragma unroll
        for (int j = 0; j < 8; ++j) {
            int id = tid + j * 256;
            int half = id >> 10;
            int rem = id & 1023;
            int row = rem >> 3, c8 = rem & 7;
            const unsigned short* Wp = half ? Wlo : Whi;
            wreg[j] = *reinterpret_cast<const u16x8*>(Wp + (size_t)(n0 + row) * K + k0 + c8 * 8);
        }
    };
    auto write_chunk = [&]() {
        #pragma unroll
        for (int j = 0; j < 4; ++j) {
            int id = tid + j * 256;
            int row = id >> 4, c4 = id & 15;
            uint2 hp, lp; cvt4(ar[j], hp, lp);
            *reinterpret_cast<uint2*>(&sA[0][row * LDR + c4 * 4]) = hp;
            *reinterpret_cast<uint2*>(&sA[1][row * LDR + c4 * 4]) = lp;
        }
        #pragma unroll
        for (int j = 0; j < 8; ++j) {
            int id = tid + j * 256;
            int half = id >> 10;
            int rem = id & 1023;
            int row = rem >> 3, c8 = rem & 7;
            *reinterpret_cast<u16x8*>(&sW[half][row * LDR + c8 * 8]) = wreg[j];
        }
    };

    load_chunk(0);
    write_chunk();
    __syncthreads();
    for (int c = 0; c < NC; ++c) {
        if (c + 1 < NC) load_chunk(c + 1);
        #pragma unroll
        for (int ks = 0; ks < 2; ++ks) {
            bf16x8 wh[2], wlv[2];
            #pragma unroll
            for (int nf = 0; nf < 2; ++nf) {
                wh[nf]  = ldsfrag(&sW[0][(w * 32 + nf * 16 + arow) * LDR + ks * 32 + koff]);
                wlv[nf] = ldsfrag(&sW[1][(w * 32 + nf * 16 + arow) * LDR + ks * 32 + koff]);
            }
            #pragma unroll
            for (int mf = 0; mf < 4; ++mf) {
                bf16x8 ah = ldsfrag(&sA[0][(mf * 16 + arow) * LDR + ks * 32 + koff]);
                bf16x8 al = ldsfrag(&sA[1][(mf * 16 + arow) * LDR + ks * 32 + koff]);
                #pragma unroll
                for (int nf = 0; nf < 2; ++nf) {
                    acc[mf][nf] = mfma16(ah, wh[nf], acc[mf][nf]);
                    acc[mf][nf] = mfma16(ah, wlv[nf], acc[mf][nf]);
                    acc[mf][nf] = mfma16(al, wh[nf], acc[mf][nf]);
                }
            }
        }
        __syncthreads();
        if (c + 1 < NC) { write_chunk(); __syncthreads(); }
    }

    #pragma unroll
    for (int mf = 0; mf < 4; ++mf) {
        #pragma unroll
        for (int nf = 0; nf < 2; ++nf) {
            int n = n0 + w * 32 + nf * 16 + arow;
            float bv = bias[n];
            #pragma unroll
            for (int r = 0; r < 4; ++r) {
                int m = m0 + mf * 16 + (lane >> 4) * 4 + r;
                float v = acc[mf][nf][r] + bv;
                if (act == 1)      v = (v > 0.f) ? v : 0.01f * v;
                else if (act == 2) v = fmaxf(v, 0.f);
                C[(size_t)m * ldc + n] = v;
            }
        }
    }
}

// ======================= small helpers =======================
__global__ __launch_bounds__(256) void concat2(
    const float* __restrict__ A, int ka,
    const float* __restrict__ Bp, int kb,
    float* __restrict__ Y, int M)
{
    int wdt = ka + kb;
    int idx = blockIdx.x * 256 + threadIdx.x;
    if (idx >= M * wdt) return;
    int m = idx / wdt, c = idx - m * wdt;
    Y[idx] = (c < ka) ? A[(size_t)m * ka + c] : Bp[(size_t)m * kb + (c - ka)];
}

__global__ __launch_bounds__(256) void reparam(
    const float* __restrict__ zmu, const float* __restrict__ zlv,
    const float* __restrict__ eps, float* __restrict__ z, int n)
{
    int i = blockIdx.x * 256 + threadIdx.x;
    if (i < n) z[i] = zmu[i] + eps[i] * __expf(0.5f * zlv[i]);
}

// ======================= host =======================
extern "C" void kernel_launch(void* const* d_in, const int* in_sizes, int n_in,
                              void* d_out, int out_size, void* d_ws, size_t ws_size,
                              hipStream_t stream)
{
    const float* past    = (const float*)d_in[0];
    const float* future  = (const float*)d_in[1];
    const float* eps     = (const float*)d_in[2];
    const float* phi_Wih = (const float*)d_in[3];
    const float* phi_Whh = (const float*)d_in[4];
    const float* phi_bih = (const float*)d_in[5];
    const float* phi_bhh = (const float*)d_in[6];
    const float* xr_Wih  = (const float*)d_in[7];
    const float* xr_Whh  = (const float*)d_in[8];
    const float* xr_bih  = (const float*)d_in[9];
    const float* xr_bhh  = (const float*)d_in[10];
    const float* mu_W1   = (const float*)d_in[11];
    const float* mu_b1   = (const float*)d_in[12];
    const float* mu_W2   = (const float*)d_in[13];
    const float* mu_b2   = (const float*)d_in[14];
    const float* mu_W3   = (const float*)d_in[15];
    const float* mu_b3   = (const float*)d_in[16];
    const float* lv_W1   = (const float*)d_in[17];
    const float* lv_b1   = (const float*)d_in[18];
    const float* lv_W2   = (const float*)d_in[19];
    const float* lv_b2   = (const float*)d_in[20];
    const float* lv_W3   = (const float*)d_in[21];
    const float* lv_b3   = (const float*)d_in[22];
    const float* dec_Wih = (const float*)d_in[23];
    const float* dec_Whh = (const float*)d_in[24];
    const float* dec_bih = (const float*)d_in[25];
    const float* dec_bhh = (const float*)d_in[26];
    const float* fc_W    = (const float*)d_in[27];
    const float* fc_b    = (const float*)d_in[28];
    const float* out_W   = (const float*)d_in[29];
    const float* out_b   = (const float*)d_in[30];
    (void)in_sizes; (void)n_in; (void)out_size; (void)ws_size;

    float* out = (float*)d_out;
    float* xmu = out;                          // (B, TL, D)
    float* zmu = out + (size_t)B * TL * D;     // (B, LD)
    float* zlv = zmu + (size_t)B * LD;

    // ---- workspace carve ----
    char* p = (char*)d_ws;
    unsigned* bars = (unsigned*)p; p += 4096;   // barrier page (memset to 0 each call)
    auto aus = [&](size_t n) { unsigned short* r = (unsigned short*)p; p += ((n * 2 + 255) / 256) * 256; return r; };
    auto af  = [&](size_t n) { float* r = (float*)p; p += ((n * 4 + 255) / 256) * 256; return r; };

    unsigned short* phiWhi = aus((size_t)3 * RU * (D + RU));
    unsigned short* phiWlo = aus((size_t)3 * RU * (D + RU));
    unsigned short* xrWhi  = aus((size_t)3 * RU * (D + RU));
    unsigned short* xrWlo  = aus((size_t)3 * RU * (D + RU));
    unsigned short* decWhi = aus((size_t)3 * HDEC * (D + HDEC));
    unsigned short* decWlo = aus((size_t)3 * HDEC * (D + HDEC));
    unsigned short* mW1hi = aus(512 * 1024), *mW1lo = aus(512 * 1024);
    unsigned short* mW2hi = aus(256 * 512),  *mW2lo = aus(256 * 512);
    unsigned short* mW3hi = aus(128 * 256),  *mW3lo = aus(128 * 256);
    unsigned short* lW1hi = aus(512 * 1024), *lW1lo = aus(512 * 1024);
    unsigned short* lW2hi = aus(256 * 512),  *lW2lo = aus(256 * 512);
    unsigned short* lW3hi = aus(128 * 256),  *lW3lo = aus(128 * 256);
    unsigned short* fcWhi = aus(512 * 640),  *fcWlo = aus(512 * 640);
    unsigned short* oWhi  = aus(128 * 512),  *oWlo  = aus(128 * 512);

    float* hA  = af((size_t)B * RU);
    float* hB  = af((size_t)B * RU);
    float* hxA = af((size_t)B * RU);
    float* hxB = af((size_t)B * RU);
    float* dh0 = af((size_t)B * HDEC);
    float* dh1 = af((size_t)B * HDEC);
    float* feat= af((size_t)B * 2 * RU);
    float* m1  = af((size_t)B * 512);
    float* m2  = af((size_t)B * 256);
    float* zb  = af((size_t)B * LD);
    float* fcb = af((size_t)B * 512);

    dim3 blk(256);

    // ---- weight split/pack ----
    split_pack<<<512, blk, 0, stream>>>(phi_Wih, phi_Whh, D, RU, 3 * RU, phiWhi, phiWlo);
    split_pack<<<512, blk, 0, stream>>>(xr_Wih,  xr_Whh,  D, RU, 3 * RU, xrWhi,  xrWlo);
    split_pack<<<512, blk, 0, stream>>>(dec_Wih, dec_Whh, D, HDEC, 3 * HDEC, decWhi, decWlo);
    split_plain<<<512, blk, 0, stream>>>(mu_W1, mW1hi, mW1lo, 512 * 1024);
    split_plain<<<256, blk, 0, stream>>>(mu_W2, mW2hi, mW2lo, 256 * 512);
    split_plain<<<128, blk, 0, stream>>>(mu_W3, mW3hi, mW3lo, 128 * 256);
    split_plain<<<512, blk, 0, stream>>>(lv_W1, lW1hi, lW1lo, 512 * 1024);
    split_plain<<<256, blk, 0, stream>>>(lv_W2, lW2hi, lW2lo, 256 * 512);
    split_plain<<<128, blk, 0, stream>>>(lv_W3, lW3hi, lW3lo, 128 * 256);
    split_plain<<<512, blk, 0, stream>>>(fc_W, fcWhi, fcWlo, 512 * 640);
    split_plain<<<128, blk, 0, stream>>>(out_W, oWhi, oWlo, 128 * 512);

    hipMemsetAsync(bars, 0, 4096, stream);
    hipMemsetAsync(hA,  0, (size_t)B * RU * sizeof(float), stream);
    hipMemsetAsync(hxA, 0, (size_t)B * RU * sizeof(float), stream);

    // ---- persistent encoders (plain launch; 128 WGs, 1 block/CU => all resident) ----
    EncArgs eP{past,   PAST * D, PAST, phiWhi, phiWlo, phi_bih, phi_bhh, hA,  hB,  bars + 0};
    EncArgs eX{future, FUT * D,  FUT,  xrWhi,  xrWlo,  xr_bih,  xr_bhh,  hxA, hxB, bars + 64};
    enc_kernel<<<dim3(128), blk, 0, stream>>>(eP, eX);
    // finals: h_past in hA, h_future in hxA (even step counts)

    concat2<<<dim3((B * 2 * RU + 255) / 256), blk, 0, stream>>>(hA, RU, hxA, RU, feat, B);

    gemm_mfma<<<dim3(2, 4), blk, 0, stream>>>(feat, 2 * RU, mW1hi, mW1lo, 1024, mu_b1, m1, 512, 1);
    gemm_mfma<<<dim3(2, 2), blk, 0, stream>>>(m1, 512, mW2hi, mW2lo, 512, mu_b2, m2, 256, 1);
    gemm_mfma<<<dim3(2, 1), blk, 0, stream>>>(m2, 256, mW3hi, mW3lo, 256, mu_b3, zmu, LD, 0);
    gemm_mfma<<<dim3(2, 4), blk, 0, stream>>>(feat, 2 * RU, lW1hi, lW1lo, 1024, lv_b1, m1, 512, 1);
    gemm_mfma<<<dim3(2, 2), blk, 0, stream>>>(m1, 512, lW2hi, lW2lo, 512, lv_b2, m2, 256, 1);
    gemm_mfma<<<dim3(2, 1), blk, 0, stream>>>(m2, 256, lW3hi, lW3lo, 256, lv_b3, zlv, LD, 0);

    reparam<<<dim3((B * LD + 255) / 256), blk, 0, stream>>>(zmu, zlv, eps, zb, B * LD);
    concat2<<<dim3((B * HDEC + 255) / 256), blk, 0, stream>>>(hA, RU, zb, LD, dh0, B);

    // ---- persistent decoder (plain launch; 80 WGs, 1 block/CU => all resident) ----
    DecArgs dA_{past + (size_t)(PAST - 1) * D, xmu,
                decWhi, decWlo, dec_bih, dec_bhh,
                fcWhi, fcWlo, fc_b,
                oWhi, oWlo, out_b,
                dh0, dh1, fcb, bars + 128};
    dec_kernel<<<dim3(80), blk, 0, stream>>>(dA_);
}

// Round 6
// 12517.695 us; speedup vs baseline: 1.4191x; 1.4191x over previous
//
#include <hip/hip_runtime.h>
#include <math.h>

// ---- problem constants ----
constexpr int B    = 128;
constexpr int PAST = 256;
constexpr int FUT  = 128;
constexpr int D    = 128;
constexpr int RU   = 512;
constexpr int LD   = 128;
constexpr int TL   = 128;
constexpr int HDEC = 640;

typedef __bf16 bf16x8 __attribute__((ext_vector_type(8)));
typedef float  f32x4  __attribute__((ext_vector_type(4)));
typedef unsigned short u16x8 __attribute__((ext_vector_type(8)));

__device__ __forceinline__ unsigned short f2bf(float f) {
    unsigned int x = __float_as_uint(f);
    x = (x + 0x7fffu + ((x >> 16) & 1u)) >> 16;
    return (unsigned short)x;
}
__device__ __forceinline__ float bf2f(unsigned short u) {
    return __uint_as_float(((unsigned int)u) << 16);
}
__device__ __forceinline__ float sigm_(float x) { return 1.f / (1.f + __expf(-x)); }
__device__ __forceinline__ float tanh_(float x) {
    float e = __expf(2.f * x);
    return 1.f - 2.f / (e + 1.f);
}
__device__ __forceinline__ bf16x8 ldsfrag(const unsigned short* p) {
    return *reinterpret_cast<const bf16x8*>(p);
}
__device__ __forceinline__ f32x4 mfma16(bf16x8 a, bf16x8 b, f32x4 c) {
    return __builtin_amdgcn_mfma_f32_16x16x32_bf16(a, b, c, 0, 0, 0);
}
__device__ __forceinline__ void cvt4(const float4& v, uint2& hp, uint2& lp) {
    float a[4] = {v.x, v.y, v.z, v.w};
    unsigned short hs[4], ls[4];
    #pragma unroll
    for (int q = 0; q < 4; ++q) { hs[q] = f2bf(a[q]); ls[q] = f2bf(a[q] - bf2f(hs[q])); }
    hp.x = (unsigned)hs[0] | ((unsigned)hs[1] << 16);
    hp.y = (unsigned)hs[2] | ((unsigned)hs[3] << 16);
    lp.x = (unsigned)ls[0] | ((unsigned)ls[1] << 16);
    lp.y = (unsigned)ls[2] | ((unsigned)ls[3] << 16);
}

// ---- coherent per-access ops (RELAXED+AGENT => per-access cache bits, NO bulk wbl2/inv) ----
__device__ __forceinline__ float ldcoh(const float* p) {
    return __hip_atomic_load(const_cast<float*>(p), __ATOMIC_RELAXED, __HIP_MEMORY_SCOPE_AGENT);
}
__device__ __forceinline__ void stcoh(float* p, float v) {
    __hip_atomic_store(p, v, __ATOMIC_RELAXED, __HIP_MEMORY_SCOPE_AGENT);
}
__device__ __forceinline__ float4 ldcoh16(const float* p) {
    const double* dp = reinterpret_cast<const double*>(p);
    double a = __hip_atomic_load(const_cast<double*>(dp),     __ATOMIC_RELAXED, __HIP_MEMORY_SCOPE_AGENT);
    double b = __hip_atomic_load(const_cast<double*>(dp + 1), __ATOMIC_RELAXED, __HIP_MEMORY_SCOPE_AGENT);
    float2 lo = *reinterpret_cast<float2*>(&a);
    float2 hi = *reinterpret_cast<float2*>(&b);
    float4 r; r.x = lo.x; r.y = lo.y; r.z = hi.x; r.w = hi.y;
    return r;
}

// arrive: drain own stores to LLC (per-wave vmcnt), join WG, one relaxed add.
__device__ __forceinline__ void bar_arrive(unsigned* cnt) {
    asm volatile("s_waitcnt vmcnt(0)" ::: "memory");
    __syncthreads();
    if (threadIdx.x == 0)
        __hip_atomic_fetch_add(cnt, 1u, __ATOMIC_RELAXED, __HIP_MEMORY_SCOPE_AGENT);
}
// wait until counter reaches tgt (relaxed spin; sc-load always reads LLC => always fresh)
__device__ __forceinline__ void bar_wait(unsigned* cnt, unsigned tgt) {
    if (threadIdx.x == 0) {
        while (__hip_atomic_load(cnt, __ATOMIC_RELAXED, __HIP_MEMORY_SCOPE_AGENT) < tgt)
            __builtin_amdgcn_s_sleep(4);
    }
    __syncthreads();
}
__device__ __forceinline__ void enc_barrier(unsigned* cnt, unsigned nwg, unsigned rnd) {
    bar_arrive(cnt);
    bar_wait(cnt, (rnd + 1u) * nwg);
}

// ======================= weight conversion =======================
__global__ __launch_bounds__(256) void split_plain(
    const float* __restrict__ W, unsigned short* __restrict__ hi,
    unsigned short* __restrict__ lo, int n)
{
    for (int i = blockIdx.x * 256 + threadIdx.x; i < n; i += gridDim.x * 256) {
        float v = W[i];
        unsigned short h = f2bf(v);
        hi[i] = h;
        lo[i] = f2bf(v - bf2f(h));
    }
}

__global__ __launch_bounds__(256) void split_pack(
    const float* __restrict__ Wih, const float* __restrict__ Whh,
    int DXc, int Hc, int N3,
    unsigned short* __restrict__ hi, unsigned short* __restrict__ lo)
{
    int K = DXc + Hc;
    int total = N3 * K;
    for (int i = blockIdx.x * 256 + threadIdx.x; i < total; i += gridDim.x * 256) {
        int n = i / K, k = i - n * K;
        float v = (k < DXc) ? Wih[(size_t)n * DXc + k]
                            : Whh[(size_t)n * Hc + (k - DXc)];
        unsigned short h = f2bf(v);
        hi[i] = h;
        lo[i] = f2bf(v - bf2f(h));
    }
}

// ======================= persistent encoder (phi + xr) =======================
struct EncArgs {
    const float* x; int xstride; int T;
    const unsigned short* Whi; const unsigned short* Wlo;  // packed (3*512, 640)
    const float* bih; const float* bhh;
    float* h0; float* h1;     // ping-pong (B, 512)
    unsigned* bar;
};

// 128 WGs x 256 thr. WGs 0..63: P, 64..127: X.
__global__ __launch_bounds__(256, 1) void enc_kernel(EncArgs P, EncArgs X)
{
    constexpr int H = 512, DX = 128, K = 640, NCH = 20, XC = 4, LDK = 648, SR = 40;
    __shared__ unsigned short sWhi[48 * LDK];
    __shared__ unsigned short sAh[2][64 * SR];
    __shared__ unsigned short sAl[2][64 * SR];
    __shared__ unsigned short sWl[2][48 * SR];

    const int wg = blockIdx.x;
    const EncArgs A = (wg < 64) ? P : X;
    const int lwg = wg & 63;
    const int m0  = (lwg & 1) * 64;
    const int c0  = (lwg >> 1) * 16;
    const int tid = threadIdx.x;
    const int lane = tid & 63;
    const int w = tid >> 6;
    const int arow = lane & 15;
    const int koff = (lane >> 4) * 8;

    for (int i = tid; i < 48 * 80; i += 256) {
        int rr = i / 80, c8 = i % 80;
        int g = rr >> 4, j = rr & 15;
        *reinterpret_cast<u16x8*>(&sWhi[rr * LDK + c8 * 8]) =
            *reinterpret_cast<const u16x8*>(A.Whi + (size_t)(g * H + c0 + j) * K + c8 * 8);
    }
    const unsigned short* wloB = nullptr;
    if (tid < 192) {
        int rr = tid >> 2, c8 = tid & 3;
        int g = rr >> 4, j = rr & 15;
        wloB = A.Wlo + (size_t)(g * H + c0 + j) * K + c8 * 8;
    }
    const int hc = c0 + arow;
    const float brz0 = A.bih[hc] + A.bhh[hc];
    const float brz1 = A.bih[H + hc] + A.bhh[H + hc];
    const float bn_i = A.bih[2 * H + hc];
    const float bn_h = A.bhh[2 * H + hc];
    __syncthreads();

    float4 ar[2]; u16x8 wl;

    for (int t = 0; t < A.T; ++t) {
        const float* hin  = (t & 1) ? A.h1 : A.h0;
        float*       hout = (t & 1) ? A.h0 : A.h1;
        const float* xp = A.x + (size_t)t * D;

        f32x4 accR = {0,0,0,0}, accZ = {0,0,0,0}, accNx = {0,0,0,0}, accNh = {0,0,0,0};

        auto ldc = [&](int c) {
            int k0 = c * 32;
            #pragma unroll
            for (int j = 0; j < 2; ++j) {
                int id = tid + j * 256;
                int row = id >> 3, c4 = id & 7;
                if (k0 < DX) {
                    ar[j] = *reinterpret_cast<const float4*>(
                        xp + (size_t)(m0 + row) * A.xstride + k0 + c4 * 4);
                } else {
                    ar[j] = ldcoh16(hin + (size_t)(m0 + row) * H + (k0 - DX) + c4 * 4);
                }
            }
            if (wloB) wl = *reinterpret_cast<const u16x8*>(wloB + k0);
        };
        auto wrc = [&](int b) {
            #pragma unroll
            for (int j = 0; j < 2; ++j) {
                int id = tid + j * 256;
                int row = id >> 3, c4 = id & 7;
                uint2 hp, lp; cvt4(ar[j], hp, lp);
                *reinterpret_cast<uint2*>(&sAh[b][row * SR + c4 * 4]) = hp;
                *reinterpret_cast<uint2*>(&sAl[b][row * SR + c4 * 4]) = lp;
            }
            if (wloB) {
                int rr = tid >> 2, c8 = tid & 3;
                *reinterpret_cast<u16x8*>(&sWl[b][rr * SR + c8 * 8]) = wl;
            }
        };

        ldc(0); wrc(0); __syncthreads();
        for (int c = 0; c < NCH; ++c) {
            const int b = c & 1;
            if (c + 1 < NCH) ldc(c + 1);
            const int aoff = (w * 16 + arow) * SR + koff;
            bf16x8 ah = ldsfrag(&sAh[b][aoff]);
            bf16x8 al = ldsfrag(&sAl[b][aoff]);
            bf16x8 whR = ldsfrag(&sWhi[(arow) * LDK + c * 32 + koff]);
            bf16x8 whZ = ldsfrag(&sWhi[(16 + arow) * LDK + c * 32 + koff]);
            bf16x8 whN = ldsfrag(&sWhi[(32 + arow) * LDK + c * 32 + koff]);
            bf16x8 wlR = ldsfrag(&sWl[b][(arow) * SR + koff]);
            bf16x8 wlZ = ldsfrag(&sWl[b][(16 + arow) * SR + koff]);
            bf16x8 wlN = ldsfrag(&sWl[b][(32 + arow) * SR + koff]);
            accR = mfma16(ah, whR, accR); accR = mfma16(ah, wlR, accR); accR = mfma16(al, whR, accR);
            accZ = mfma16(ah, whZ, accZ); accZ = mfma16(ah, wlZ, accZ); accZ = mfma16(al, whZ, accZ);
            if (c < XC) {
                accNx = mfma16(ah, whN, accNx); accNx = mfma16(ah, wlN, accNx); accNx = mfma16(al, whN, accNx);
            } else {
                accNh = mfma16(ah, whN, accNh); accNh = mfma16(ah, wlN, accNh); accNh = mfma16(al, whN, accNh);
            }
            if (c + 1 < NCH) wrc(b ^ 1);
            __syncthreads();
        }

        #pragma unroll
        for (int r = 0; r < 4; ++r) {
            int m = m0 + w * 16 + (lane >> 4) * 4 + r;
            float rg = sigm_(accR[r] + brz0);
            float zg = sigm_(accZ[r] + brz1);
            float ng = tanh_((accNx[r] + bn_i) + rg * (accNh[r] + bn_h));
            float ho = ldcoh(hin + (size_t)m * H + hc);
            stcoh(hout + (size_t)m * H + hc, (1.f - zg) * ng + zg * ho);
        }
        enc_barrier(A.bar, 64, (unsigned)t);
    }
}

// ======================= persistent decoder =======================
struct DecArgs {
    const float* past_last;    // past + 255*D, row stride PAST*D
    float* xmu;                // d_out, (B, TL, D)
    const unsigned short* Whi; const unsigned short* Wlo;   // dec packed (1920, 768)
    const float* bih; const float* bhh;
    const unsigned short* fcWhi; const unsigned short* fcWlo; // (512, 640)
    const float* fc_b;
    const unsigned short* oWhi; const unsigned short* oWlo;   // (128, 512)
    const float* out_b;
    float* dh0; float* dh1; float* fcb;
    unsigned* cA; unsigned* cB; unsigned* cC;
};

// plain streamed GEMM for one 16-col tile, M=128, per-wave 2 m-frags; src/dst coherent
__device__ __forceinline__ void plain16(
    unsigned short* smem, int whi_ush, int ldk, int nch,
    const float* src, int srcld,
    const unsigned short* wloB,
    float bias_v, int mode,
    float* dst, long dld, int dcol0,
    int tid, int w, int lane, int arow, int koff)
{
    unsigned short* AH[2] = { smem + whi_ush,          smem + whi_ush + 5120 };
    unsigned short* AL[2] = { smem + whi_ush + 10240,  smem + whi_ush + 15360 };
    unsigned short* WL[2] = { smem + whi_ush + 20480,  smem + whi_ush + 21120 };
    f32x4 acc0 = {0,0,0,0}, acc1 = {0,0,0,0};
    float4 ar[4]; u16x8 wl;
    auto ldc = [&](int c) {
        int k0 = c * 32;
        #pragma unroll
        for (int j = 0; j < 4; ++j) {
            int id = tid + j * 256, row = id >> 3, c4 = id & 7;
            ar[j] = ldcoh16(src + (size_t)row * srcld + k0 + c4 * 4);
        }
        if (wloB) wl = *reinterpret_cast<const u16x8*>(wloB + k0);
    };
    auto wrc = [&](int b) {
        #pragma unroll
        for (int j = 0; j < 4; ++j) {
            int id = tid + j * 256, row = id >> 3, c4 = id & 7;
            uint2 hp, lp; cvt4(ar[j], hp, lp);
            *reinterpret_cast<uint2*>(&AH[b][row * 40 + c4 * 4]) = hp;
            *reinterpret_cast<uint2*>(&AL[b][row * 40 + c4 * 4]) = lp;
        }
        if (wloB) {
            int rr = tid >> 2, c8 = tid & 3;
            *reinterpret_cast<u16x8*>(&WL[b][rr * 40 + c8 * 8]) = wl;
        }
    };
    ldc(0); wrc(0); __syncthreads();
    for (int c = 0; c < nch; ++c) {
        int b = c & 1;
        if (c + 1 < nch) ldc(c + 1);
        int a0 = (w * 32 + arow) * 40 + koff;
        bf16x8 ah0 = ldsfrag(&AH[b][a0]),       al0 = ldsfrag(&AL[b][a0]);
        bf16x8 ah1 = ldsfrag(&AH[b][a0 + 640]), al1 = ldsfrag(&AL[b][a0 + 640]);
        bf16x8 wh  = ldsfrag(&smem[arow * ldk + c * 32 + koff]);
        bf16x8 wlg = ldsfrag(&WL[b][arow * 40 + koff]);
        acc0 = mfma16(ah0, wh, acc0); acc0 = mfma16(ah0, wlg, acc0); acc0 = mfma16(al0, wh, acc0);
        acc1 = mfma16(ah1, wh, acc1); acc1 = mfma16(ah1, wlg, acc1); acc1 = mfma16(al1, wh, acc1);
        if (c + 1 < nch) wrc(b ^ 1);
        __syncthreads();
    }
    #pragma unroll
    for (int mf = 0; mf < 2; ++mf) {
        f32x4 a = mf ? acc1 : acc0;
        #pragma unroll
        for (int r = 0; r < 4; ++r) {
            int m = w * 32 + mf * 16 + (lane >> 4) * 4 + r;
            float v = a[r] + bias_v;
            if (mode == 1) v = fmaxf(v, 0.f);
            stcoh(dst + (size_t)m * dld + dcol0 + arow, v);
        }
    }
}

__device__ __forceinline__ void dec_gru(
    unsigned short* smem, const DecArgs& A, int t,
    const float* hcur, float* hnext,
    int c0, const unsigned short* wloB,
    float brz0, float brz1, float bn_i, float bn_h,
    int tid, int w, int lane, int arow, int koff)
{
    unsigned short* AH[2] = { smem + 37248, smem + 42368 };
    unsigned short* AL[2] = { smem + 47488, smem + 52608 };
    unsigned short* WL[2] = { smem + 57728, smem + 59648 };
    const float* xp; long xs;
    if (t == 0) { xp = A.past_last; xs = (long)PAST * D; }
    else        { xp = A.xmu + (size_t)(t - 1) * D; xs = (long)TL * D; }

    f32x4 aR0 = {0,0,0,0}, aZ0 = aR0, aNx0 = aR0, aNh0 = aR0;
    f32x4 aR1 = aR0, aZ1 = aR0, aNx1 = aR0, aNh1 = aR0;
    float4 ar[4]; u16x8 wl;
    auto ldc = [&](int c) {
        int k0 = c * 32;
        #pragma unroll
        for (int j = 0; j < 4; ++j) {
            int id = tid + j * 256, row = id >> 3, c4 = id & 7;
            const float* s = (k0 < D)
                ? (xp + (size_t)row * xs + k0 + c4 * 4)
                : (hcur + (size_t)row * HDEC + (k0 - D) + c4 * 4);
            ar[j] = ldcoh16(s);     // xmu feedback + h are both cross-WG
        }
        if (wloB) wl = *reinterpret_cast<const u16x8*>(wloB + k0);
    };
    auto wrc = [&](int b) {
        #pragma unroll
        for (int j = 0; j < 4; ++j) {
            int id = tid + j * 256, row = id >> 3, c4 = id & 7;
            uint2 hp, lp; cvt4(ar[j], hp, lp);
            *reinterpret_cast<uint2*>(&AH[b][row * 40 + c4 * 4]) = hp;
            *reinterpret_cast<uint2*>(&AL[b][row * 40 + c4 * 4]) = lp;
        }
        if (wloB) {
            int rr = tid >> 2, c8 = tid & 3;
            *reinterpret_cast<u16x8*>(&WL[b][rr * 40 + c8 * 8]) = wl;
        }
    };
    ldc(0); wrc(0); __syncthreads();
    for (int c = 0; c < 24; ++c) {
        int b = c & 1;
        if (c + 1 < 24) ldc(c + 1);
        int a0 = (w * 32 + arow) * 40 + koff;
        bf16x8 ah0 = ldsfrag(&AH[b][a0]),       al0 = ldsfrag(&AL[b][a0]);
        bf16x8 ah1 = ldsfrag(&AH[b][a0 + 640]), al1 = ldsfrag(&AL[b][a0 + 640]);
        bf16x8 whR = ldsfrag(&smem[(arow) * 776 + c * 32 + koff]);
        bf16x8 whZ = ldsfrag(&smem[(16 + arow) * 776 + c * 32 + koff]);
        bf16x8 whN = ldsfrag(&smem[(32 + arow) * 776 + c * 32 + koff]);
        bf16x8 wlR = ldsfrag(&WL[b][(arow) * 40 + koff]);
        bf16x8 wlZ = ldsfrag(&WL[b][(16 + arow) * 40 + koff]);
        bf16x8 wlN = ldsfrag(&WL[b][(32 + arow) * 40 + koff]);
        aR0 = mfma16(ah0, whR, aR0); aR0 = mfma16(ah0, wlR, aR0); aR0 = mfma16(al0, whR, aR0);
        aR1 = mfma16(ah1, whR, aR1); aR1 = mfma16(ah1, wlR, aR1); aR1 = mfma16(al1, whR, aR1);
        aZ0 = mfma16(ah0, whZ, aZ0); aZ0 = mfma16(ah0, wlZ, aZ0); aZ0 = mfma16(al0, whZ, aZ0);
        aZ1 = mfma16(ah1, whZ, aZ1); aZ1 = mfma16(ah1, wlZ, aZ1); aZ1 = mfma16(al1, whZ, aZ1);
        if (c < 4) {
            aNx0 = mfma16(ah0, whN, aNx0); aNx0 = mfma16(ah0, wlN, aNx0); aNx0 = mfma16(al0, whN, aNx0);
            aNx1 = mfma16(ah1, whN, aNx1); aNx1 = mfma16(ah1, wlN, aNx1); aNx1 = mfma16(al1, whN, aNx1);
        } else {
            aNh0 = mfma16(ah0, whN, aNh0); aNh0 = mfma16(ah0, wlN, aNh0); aNh0 = mfma16(al0, whN, aNh0);
            aNh1 = mfma16(ah1, whN, aNh1); aNh1 = mfma16(ah1, wlN, aNh1); aNh1 = mfma16(al1, whN, aNh1);
        }
        if (c + 1 < 24) wrc(b ^ 1);
        __syncthreads();
    }
    const int hcc = c0 + arow;
    #pragma unroll
    for (int mf = 0; mf < 2; ++mf) {
        #pragma unroll
        for (int r = 0; r < 4; ++r) {
            int m = w * 32 + mf * 16 + (lane >> 4) * 4 + r;
            float vr = mf ? aR1[r] : aR0[r];
            float vz = mf ? aZ1[r] : aZ0[r];
            float vx = mf ? aNx1[r] : aNx0[r];
            float vh = mf ? aNh1[r] : aNh0[r];
            float rg = sigm_(vr + brz0);
            float zg = sigm_(vz + brz1);
            float ng = tanh_((vx + bn_i) + rg * (vh + bn_h));
            float ho = ldcoh(hcur + (size_t)m * HDEC + hcc);
            stcoh(hnext + (size_t)m * HDEC + hcc, (1.f - zg) * ng + zg * ho);
        }
    }
}

// 80 WGs: 0..39 GRU (16 cols each of 640), 40..71 fc (16 of 512), 72..79 out (16 of 128)
// producer-count sub-barriers: role0 -> cA (40), role1 -> cB (32), role2 -> cC (8)
__global__ __launch_bounds__(256, 1) void dec_kernel(DecArgs A)
{
    __shared__ unsigned short smem[61568];   // 123136 B -> 1 block/CU
    const int wg = blockIdx.x;
    const int tid = threadIdx.x;
    const int lane = tid & 63;
    const int w = tid >> 6;
    const int arow = lane & 15;
    const int koff = (lane >> 4) * 8;
    const int role = (wg < 40) ? 0 : ((wg < 72) ? 1 : 2);

    const unsigned short* wloB = nullptr;
    float b0 = 0, b1 = 0, b2 = 0, b3 = 0;
    int c0 = 0;

    if (role == 0) {
        c0 = wg * 16;
        for (int i = tid; i < 4608; i += 256) {
            int rr = i / 96, c8 = i % 96;
            int g = rr >> 4, j = rr & 15;
            *reinterpret_cast<u16x8*>(&smem[rr * 776 + c8 * 8]) =
                *reinterpret_cast<const u16x8*>(A.Whi + (size_t)(g * HDEC + c0 + j) * 768 + c8 * 8);
        }
        if (tid < 192) {
            int rr = tid >> 2, c8 = tid & 3;
            int g = rr >> 4, j = rr & 15;
            wloB = A.Wlo + (size_t)(g * HDEC + c0 + j) * 768 + c8 * 8;
        }
        int hcc = c0 + arow;
        b0 = A.bih[hcc] + A.bhh[hcc];
        b1 = A.bih[HDEC + hcc] + A.bhh[HDEC + hcc];
        b2 = A.bih[2 * HDEC + hcc];
        b3 = A.bhh[2 * HDEC + hcc];
    } else if (role == 1) {
        c0 = (wg - 40) * 16;
        for (int i = tid; i < 1280; i += 256) {
            int rr = i / 80, c8 = i % 80;
            *reinterpret_cast<u16x8*>(&smem[rr * 648 + c8 * 8]) =
                *reinterpret_cast<const u16x8*>(A.fcWhi + (size_t)(c0 + rr) * 640 + c8 * 8);
        }
        if (tid < 64) {
            int rr = tid >> 2, c8 = tid & 3;
            wloB = A.fcWlo + (size_t)(c0 + rr) * 640 + c8 * 8;
        }
        b0 = A.fc_b[c0 + arow];
    } else {
        c0 = (wg - 72) * 16;
        for (int i = tid; i < 1024; i += 256) {
            int rr = i >> 6, c8 = i & 63;
            *reinterpret_cast<u16x8*>(&smem[rr * 520 + c8 * 8]) =
                *reinterpret_cast<const u16x8*>(A.oWhi + (size_t)(c0 + rr) * 512 + c8 * 8);
        }
        if (tid < 64) {
            int rr = tid >> 2, c8 = tid & 3;
            wloB = A.oWlo + (size_t)(c0 + rr) * 512 + c8 * 8;
        }
        b0 = A.out_b[c0 + arow];
    }
    __syncthreads();

    for (int t = 0; t < TL; ++t) {
        const float* hcur  = (t & 1) ? A.dh1 : A.dh0;
        float*       hnext = (t & 1) ? A.dh0 : A.dh1;
        if (role == 0) {
            if (t > 0) bar_wait(A.cC, (unsigned)t * 8);   // xmu[t-1] ready
            dec_gru(smem, A, t, hcur, hnext, c0, wloB, b0, b1, b2, b3, tid, w, lane, arow, koff);
            bar_arrive(A.cA);
        } else if (role == 1) {
            bar_wait(A.cA, (unsigned)(t + 1) * 40);       // hnext ready
            plain16(smem, 10368, 648, 20, hnext, HDEC, wloB, b0, 1, A.fcb, 512, c0,
                    tid, w, lane, arow, koff);
            bar_arrive(A.cB);
        } else {
            bar_wait(A.cB, (unsigned)(t + 1) * 32);       // fcb ready
            plain16(smem, 8320, 520, 16, A.fcb, 512, wloB, b0, 0,
                    A.xmu + (size_t)t * D, (long)TL * D, c0, tid, w, lane, arow, koff);
            bar_arrive(A.cC);
        }
    }
}

// ======================= MLP GEMM (r2, proven) =======================
__global__ __launch_bounds__(256, 1) void gemm_mfma(
    const float* __restrict__ A, int lda,
    const unsigned short* __restrict__ Whi, const unsigned short* __restrict__ Wlo,
    int K, const float* __restrict__ bias,
    float* __restrict__ C, int ldc, int act)
{
    constexpr int LDR = 72;
    __shared__ unsigned short sA[2][64 * LDR];
    __shared__ unsigned short sW[2][128 * LDR];

    const int m0 = blockIdx.x * 64;
    const int n0 = blockIdx.y * 128;
    const int tid = threadIdx.x;
    const int lane = tid & 63;
    const int w = tid >> 6;
    const int arow = lane & 15;
    const int koff = (lane >> 4) * 8;

    f32x4 acc[4][2];
    #pragma unroll
    for (int i = 0; i < 4; ++i) { acc[i][0] = f32x4{0,0,0,0}; acc[i][1] = f32x4{0,0,0,0}; }

    float4 ar[4];
    u16x8  wreg[8];
    const int NC = K / 64;

    auto load_chunk = [&](int c) {
        const int k0 = c * 64;
        #pragma unroll
        for (int j = 0; j < 4; ++j) {
            int id = tid + j * 256;
            int row = id >> 4, c4 = id & 15;
            ar[j] = *reinterpret_cast<const float4*>(A + (size_t)(m0 + row) * lda + k0 + c4 * 4);
        }
        #pragma unroll
        for (int j = 0; j < 8; ++j) {
            int id = tid + j * 256;
            int half = id >> 10;
            int rem = id & 1023;
            int row = rem >> 3, c8 = rem & 7;
            const unsigned short* Wp = half ? Wlo : Whi;
            wreg[j] = *reinterpret_cast<const u16x8*>(Wp + (size_t)(n0 + row) * K + k0 + c8 * 8);
        }
    };
    auto write_chunk = [&]() {
        #pragma unroll
        for (int j = 0; j < 4; ++j) {
            int id = tid + j * 256;
            int row = id >> 4, c4 = id & 15;
            uint2 hp, lp; cvt4(ar[j], hp, lp);
            *reinterpret_cast<uint2*>(&sA[0][row * LDR + c4 * 4]) = hp;
            *reinterpret_cast<uint2*>(&sA[1][row * LDR + c4 * 4]) = lp;
        }
        #pragma unroll
        for (int j = 0; j < 8; ++j) {
            int id = tid + j * 256;
            int half = id >> 10;
            int rem = id & 1023;
            int row = rem >> 3, c8 = rem & 7;
            *reinterpret_cast<u16x8*>(&sW[half][row * LDR + c8 * 8]) = wreg[j];
        }
    };

    load_chunk(0);
    write_chunk();
    __syncthreads();
    for (int c = 0; c < NC; ++c) {
        if (c + 1 < NC) load_chunk(c + 1);
        #pragma unroll
        for (int ks = 0; ks < 2; ++ks) {
            bf16x8 wh[2], wlv[2];
            #pragma unroll
            for (int nf = 0; nf < 2; ++nf) {
                wh[nf]  = ldsfrag(&sW[0][(w * 32 + nf * 16 + arow) * LDR + ks * 32 + koff]);
                wlv[nf] = ldsfrag(&sW[1][(w * 32 + nf * 16 + arow) * LDR + ks * 32 + koff]);
            }
            #pragma unroll
            for (int mf = 0; mf < 4; ++mf) {
                bf16x8 ah = ldsfrag(&sA[0][(mf * 16 + arow) * LDR + ks * 32 + koff]);
                bf16x8 al = ldsfrag(&sA[1][(mf * 16 + arow) * LDR + ks * 32 + koff]);
                #pragma unroll
                for (int nf = 0; nf < 2; ++nf) {
                    acc[mf][nf] = mfma16(ah, wh[nf], acc[mf][nf]);
                    acc[mf][nf] = mfma16(ah, wlv[nf], acc[mf][nf]);
                    acc[mf][nf] = mfma16(al, wh[nf], acc[mf][nf]);
                }
            }
        }
        __syncthreads();
        if (c + 1 < NC) { write_chunk(); __syncthreads(); }
    }

    #pragma unroll
    for (int mf = 0; mf < 4; ++mf) {
        #pragma unroll
        for (int nf = 0; nf < 2; ++nf) {
            int n = n0 + w * 32 + nf * 16 + arow;
            float bv = bias[n];
            #pragma unroll
            for (int r = 0; r < 4; ++r) {
                int m = m0 + mf * 16 + (lane >> 4) * 4 + r;
                float v = acc[mf][nf][r] + bv;
                if (act == 1)      v = (v > 0.f) ? v : 0.01f * v;
                else if (act == 2) v = fmaxf(v, 0.f);
                C[(size_t)m * ldc + n] = v;
            }
        }
    }
}

// ======================= small helpers =======================
__global__ __launch_bounds__(256) void concat2(
    const float* __restrict__ A, int ka,
    const float* __restrict__ Bp, int kb,
    float* __restrict__ Y, int M)
{
    int wdt = ka + kb;
    int idx = blockIdx.x * 256 + threadIdx.x;
    if (idx >= M * wdt) return;
    int m = idx / wdt, c = idx - m * wdt;
    Y[idx] = (c < ka) ? A[(size_t)m * ka + c] : Bp[(size_t)m * kb + (c - ka)];
}

__global__ __launch_bounds__(256) void reparam(
    const float* __restrict__ zmu, const float* __restrict__ zlv,
    const float* __restrict__ eps, float* __restrict__ z, int n)
{
    int i = blockIdx.x * 256 + threadIdx.x;
    if (i < n) z[i] = zmu[i] + eps[i] * __expf(0.5f * zlv[i]);
}

// ======================= host =======================
extern "C" void kernel_launch(void* const* d_in, const int* in_sizes, int n_in,
                              void* d_out, int out_size, void* d_ws, size_t ws_size,
                              hipStream_t stream)
{
    const float* past    = (const float*)d_in[0];
    const float* future  = (const float*)d_in[1];
    const float* eps     = (const float*)d_in[2];
    const float* phi_Wih = (const float*)d_in[3];
    const float* phi_Whh = (const float*)d_in[4];
    const float* phi_bih = (const float*)d_in[5];
    const float* phi_bhh = (const float*)d_in[6];
    const float* xr_Wih  = (const float*)d_in[7];
    const float* xr_Whh  = (const float*)d_in[8];
    const float* xr_bih  = (const float*)d_in[9];
    const float* xr_bhh  = (const float*)d_in[10];
    const float* mu_W1   = (const float*)d_in[11];
    const float* mu_b1   = (const float*)d_in[12];
    const float* mu_W2   = (const float*)d_in[13];
    const float* mu_b2   = (const float*)d_in[14];
    const float* mu_W3   = (const float*)d_in[15];
    const float* mu_b3   = (const float*)d_in[16];
    const float* lv_W1   = (const float*)d_in[17];
    const float* lv_b1   = (const float*)d_in[18];
    const float* lv_W2   = (const float*)d_in[19];
    const float* lv_b2   = (const float*)d_in[20];
    const float* lv_W3   = (const float*)d_in[21];
    const float* lv_b3   = (const float*)d_in[22];
    const float* dec_Wih = (const float*)d_in[23];
    const float* dec_Whh = (const float*)d_in[24];
    const float* dec_bih = (const float*)d_in[25];
    const float* dec_bhh = (const float*)d_in[26];
    const float* fc_W    = (const float*)d_in[27];
    const float* fc_b    = (const float*)d_in[28];
    const float* out_W   = (const float*)d_in[29];
    const float* out_b   = (const float*)d_in[30];
    (void)in_sizes; (void)n_in; (void)out_size; (void)ws_size;

    float* out = (float*)d_out;
    float* xmu = out;                          // (B, TL, D)
    float* zmu = out + (size_t)B * TL * D;     // (B, LD)
    float* zlv = zmu + (size_t)B * LD;

    // ---- workspace carve ----
    char* p = (char*)d_ws;
    unsigned* bars = (unsigned*)p; p += 4096;   // barrier page (memset to 0 each call)
    auto aus = [&](size_t n) { unsigned short* r = (unsigned short*)p; p += ((n * 2 + 255) / 256) * 256; return r; };
    auto af  = [&](size_t n) { float* r = (float*)p; p += ((n * 4 + 255) / 256) * 256; return r; };

    unsigned short* phiWhi = aus((size_t)3 * RU * (D + RU));
    unsigned short* phiWlo = aus((size_t)3 * RU * (D + RU));
    unsigned short* xrWhi  = aus((size_t)3 * RU * (D + RU));
    unsigned short* xrWlo  = aus((size_t)3 * RU * (D + RU));
    unsigned short* decWhi = aus((size_t)3 * HDEC * (D + HDEC));
    unsigned short* decWlo = aus((size_t)3 * HDEC * (D + HDEC));
    unsigned short* mW1hi = aus(512 * 1024), *mW1lo = aus(512 * 1024);
    unsigned short* mW2hi = aus(256 * 512),  *mW2lo = aus(256 * 512);
    unsigned short* mW3hi = aus(128 * 256),  *mW3lo = aus(128 * 256);
    unsigned short* lW1hi = aus(512 * 1024), *lW1lo = aus(512 * 1024);
    unsigned short* lW2hi = aus(256 * 512),  *lW2lo = aus(256 * 512);
    unsigned short* lW3hi = aus(128 * 256),  *lW3lo = aus(128 * 256);
    unsigned short* fcWhi = aus(512 * 640),  *fcWlo = aus(512 * 640);
    unsigned short* oWhi  = aus(128 * 512),  *oWlo  = aus(128 * 512);

    float* hA  = af((size_t)B * RU);
    float* hB  = af((size_t)B * RU);
    float* hxA = af((size_t)B * RU);
    float* hxB = af((size_t)B * RU);
    float* dh0 = af((size_t)B * HDEC);
    float* dh1 = af((size_t)B * HDEC);
    float* feat= af((size_t)B * 2 * RU);
    float* m1  = af((size_t)B * 512);
    float* m2  = af((size_t)B * 256);
    float* zb  = af((size_t)B * LD);
    float* fcb = af((size_t)B * 512);

    dim3 blk(256);

    // ---- weight split/pack ----
    split_pack<<<512, blk, 0, stream>>>(phi_Wih, phi_Whh, D, RU, 3 * RU, phiWhi, phiWlo);
    split_pack<<<512, blk, 0, stream>>>(xr_Wih,  xr_Whh,  D, RU, 3 * RU, xrWhi,  xrWlo);
    split_pack<<<512, blk, 0, stream>>>(dec_Wih, dec_Whh, D, HDEC, 3 * HDEC, decWhi, decWlo);
    split_plain<<<512, blk, 0, stream>>>(mu_W1, mW1hi, mW1lo, 512 * 1024);
    split_plain<<<256, blk, 0, stream>>>(mu_W2, mW2hi, mW2lo, 256 * 512);
    split_plain<<<128, blk, 0, stream>>>(mu_W3, mW3hi, mW3lo, 128 * 256);
    split_plain<<<512, blk, 0, stream>>>(lv_W1, lW1hi, lW1lo, 512 * 1024);
    split_plain<<<256, blk, 0, stream>>>(lv_W2, lW2hi, lW2lo, 256 * 512);
    split_plain<<<128, blk, 0, stream>>>(lv_W3, lW3hi, lW3lo, 128 * 256);
    split_plain<<<512, blk, 0, stream>>>(fc_W, fcWhi, fcWlo, 512 * 640);
    split_plain<<<128, blk, 0, stream>>>(out_W, oWhi, oWlo, 128 * 512);

    hipMemsetAsync(bars, 0, 4096, stream);
    hipMemsetAsync(hA,  0, (size_t)B * RU * sizeof(float), stream);
    hipMemsetAsync(hxA, 0, (size_t)B * RU * sizeof(float), stream);

    // ---- persistent encoders (plain launch; 128 WGs, 1 block/CU => all resident) ----
    EncArgs eP{past,   PAST * D, PAST, phiWhi, phiWlo, phi_bih, phi_bhh, hA,  hB,  bars + 0};
    EncArgs eX{future, FUT * D,  FUT,  xrWhi,  xrWlo,  xr_bih,  xr_bhh,  hxA, hxB, bars + 64};
    enc_kernel<<<dim3(128), blk, 0, stream>>>(eP, eX);
    // finals: h_past in hA, h_future in hxA (even step counts)

    concat2<<<dim3((B * 2 * RU + 255) / 256), blk, 0, stream>>>(hA, RU, hxA, RU, feat, B);

    gemm_mfma<<<dim3(2, 4), blk, 0, stream>>>(feat, 2 * RU, mW1hi, mW1lo, 1024, mu_b1, m1, 512, 1);
    gemm_mfma<<<dim3(2, 2), blk, 0, stream>>>(m1, 512, mW2hi, mW2lo, 512, mu_b2, m2, 256, 1);
    gemm_mfma<<<dim3(2, 1), blk, 0, stream>>>(m2, 256, mW3hi, mW3lo, 256, mu_b3, zmu, LD, 0);
    gemm_mfma<<<dim3(2, 4), blk, 0, stream>>>(feat, 2 * RU, lW1hi, lW1lo, 1024, lv_b1, m1, 512, 1);
    gemm_mfma<<<dim3(2, 2), blk, 0, stream>>>(m1, 512, lW2hi, lW2lo, 512, lv_b2, m2, 256, 1);
    gemm_mfma<<<dim3(2, 1), blk, 0, stream>>>(m2, 256, lW3hi, lW3lo, 256, lv_b3, zlv, LD, 0);

    reparam<<<dim3((B * LD + 255) / 256), blk, 0, stream>>>(zmu, zlv, eps, zb, B * LD);
    concat2<<<dim3((B * HDEC + 255) / 256), blk, 0, stream>>>(hA, RU, zb, LD, dh0, B);

    // ---- persistent decoder (plain launch; 80 WGs, 1 block/CU => all resident) ----
    DecArgs dA_{past + (size_t)(PAST - 1) * D, xmu,
                decWhi, decWlo, dec_bih, dec_bhh,
                fcWhi, fcWlo, fc_b,
                oWhi, oWlo, out_b,
                dh0, dh1, fcb,
                bars + 128, bars + 192, bars + 256};
    dec_kernel<<<dim3(80), blk, 0, stream>>>(dA_);
}